// Round 6
// baseline (361.551 us; speedup 1.0000x reference)
//
#include <hip/hip_runtime.h>

// CostTokenizer R12: double wave concurrency — 8-way C-split, 512-thr blocks.
//   Post-mortem R9-R11: compiler pins VGPR at the 64-reg/8-wave boundary and
//   defeats every source-level ILP scheme (prefetch spilled/slowed, win[7]
//   re-sunk). R8 analysis: ALL pipes 24-37% busy (VALU 26.6us, LDS ~17us,
//   HBM ~23us of a 72us kernel) with 16 waves/CU and ILP~2 -> latency-bound;
//   the scarce resource is RESIDENT WAVES. Grid is maxed (1344 tiles, 1
//   wave-tile = 64 px min), blocks/CU maxed (4), so deepen the C-split:
//   8 waves/block (512 thr), C/8 per wave (L1:2 chunks, L2:4, L3:6).
//   LDS = 8 x 4.16KB halos = 33.3KB (reduce slices alias) -> 4 blocks/CU;
//   VGPR 64 -> 32 waves/CU, 2x R8. Cross-wave reduce: waves 0,1 store the
//   two [49][64] slices, barrier, waves 2-7 ds_add_f32 (atomicAdd on LDS),
//   barrier. Phase 3: d split 8 ways (24/wave, sA[24]).
//   __launch_bounds__(512,8) targets exactly the 64-reg boundary the
//   compiler picks voluntarily (R8/R11 both 64 with identical live state).
//   Spill gate: WRITE_SIZE must stay exactly 64,512 KB, else revert bound.
//  - RULE (R9): never force a VGPR budget below the natural live state
//    (~60 regs here); 64 is the floor we request, not below.
//  - R6 rule kept: every loop indexing a register array is fully unrolled;
//    `unroll 1` only on loops touching LDS/global alone (scratch-spill trap).
//  - bank conflicts ~5.6M are ~free 2-way aliasing (m136); phase-1 b128
//    reads conflict-free within 8-lane groups.
//  - LDS union (slices [0,6272) floats alias waves 0-6 halos, all dead at
//    the first barrier) + XCD column swizzle.
//
//  corr[k] = sum_c f1[c,h,w] * f2[c, (h-dy)%H, (w-dx)%W], k = (dy+3)*7 + (dx+3)
//  tok[t,b,d,h,w] = b[d] + (1/sqrt(C)) * sum_k corr[k] * w[k,d]

#define TD 192
#define HSTRIDE 26   // halo row stride in float4

template<int C, int H, int W, int TX, int TY>
__device__ __forceinline__ void level_tile(
    const float* __restrict__ lvl, const float* __restrict__ wm,
    const float* __restrict__ bias, float* __restrict__ out,
    int r, float scale, float* __restrict__ smem)
{
    const int HW = H * W;
    // XCD column-affinity: tiles of one column (pair,tX) are == mod 8 in bid
    const int xcd = r & 7, q = r >> 3;
    const int tY  = q % TY;
    const int col = (q / TY) * 8 + xcd;      // [0, 4*TX)
    const int pair = col / TX, tX = col % TX;

    const int t  = pair >> 1, bb = pair & 1;
    const float* f1 = lvl + (t * 2 + bb) * C * HW;
    const float* f2 = lvl + ((t + 1) * 2 + bb) * C * HW;

    const int tid  = threadIdx.x;
    const int lane = tid & 63;
    const int g    = tid >> 6;               // wave: channel group, 0..7
    const int tx   = lane & 15, ty = lane >> 4;   // lane owns row y0+ty
    const int x0   = tX * 16, y0 = tY * 4;
    const int x    = x0 + tx;
    const int y    = y0 + ty;

    float4* h = (float4*)smem + g * (10 * HSTRIDE);  // wave halo: 10 rows

    // staging offsets for halo cells p in [0,220): row=p/22, col=p%22
    int goff[4], loff[4];
#pragma unroll
    for (int i = 0; i < 4; ++i) {
        int p = lane + i * 64;
        int rr = p / 22, cc = p - rr * 22;
        int gy = y0 - 3 + rr; if (gy < 0) gy += H; if (gy >= H) gy -= H;
        int gx = x0 - 3 + cc; if (gx < 0) gx += W; if (gx >= W) gx -= W;
        goff[i] = gy * W + gx;
        loff[i] = rr * HSTRIDE + cc;
    }

    float acc[49];
#pragma unroll
    for (int k = 0; k < 49; ++k) acc[k] = 0.f;

    // ---- phase 1: correlation, wave-synchronous (wave-private halo) ----
    const int NCH = C / 32;                  // 4-channel chunks per wave (8-way split)
    const float* f2c = f2 + g * (C / 8) * HW;
    const float* f1c = f1 + g * (C / 8) * HW + y * W + x;
#pragma unroll 1
    for (int cg = 0; cg < NCH; ++cg) {       // body touches LDS/global only via
#pragma unroll                               // fully-unrolled inner loops
        for (int i = 0; i < 4; ++i) {
            if (i < 3 || lane < 28) {        // 220 cells
                const float* s = f2c + goff[i];
                float4 v; v.x = s[0]; v.y = s[HW]; v.z = s[2 * HW]; v.w = s[3 * HW];
                h[loff[i]] = v;
            }
        }
        float a0 = f1c[0], a1 = f1c[HW], a2 = f1c[2 * HW], a3 = f1c[3 * HW];
        f2c += 4 * HW; f1c += 4 * HW;
        // same-wave LDS RAW: compiler lgkmcnt waits cover it
#pragma unroll
        for (int b = 0; b < 7; ++b) {        // FULL unroll: indexes acc
            const float4* hp = h + ty * HSTRIDE + (tx + 6 - b);
#pragma unroll
            for (int a = 0; a < 7; ++a) {
                float4 lo = hp[(6 - a) * HSTRIDE];
                float s0 = acc[a * 7 + b];
                s0 = fmaf(a0, lo.x, s0); s0 = fmaf(a1, lo.y, s0);
                s0 = fmaf(a2, lo.z, s0); s0 = fmaf(a3, lo.w, s0);
                acc[a * 7 + b] = s0;
            }
        }
    }

    // ---- phase 2: cross-wave reduce; slices alias dead halo space ----
    __syncthreads();                         // all waves done with halos
    float* s0p = smem;                       // [49][64]
    float* s1p = smem + 49 * 64;
    if (g < 2) {                             // waves 0,1 seed the two slices
        float* dst = g ? s1p : s0p;
#pragma unroll
        for (int k = 0; k < 49; ++k)         // FULL unroll: indexes acc
            dst[k * 64 + lane] = acc[k];
    }
    __syncthreads();                         // seeds visible before adds
    if (g >= 2) {                            // waves 2-7: native ds_add_f32
        float* dst = (g & 1) ? s1p : s0p;
#pragma unroll
        for (int k = 0; k < 49; ++k)         // FULL unroll: indexes acc
            atomicAdd(&dst[k * 64 + lane], acc[k]);
    }
    __syncthreads();

    // ---- phase 3: 49 -> 192, wave g owns d in [24g, 24g+24), 1 px/lane ----
    const int dbase = __builtin_amdgcn_readfirstlane(g * 24);
    float sA[24];
#pragma unroll
    for (int j = 0; j < 24; ++j) sA[j] = bias[dbase + j];
#pragma unroll 2
    for (int k = 0; k < 49; ++k) {           // unroll 2: two w-rows in flight
        float c0 = (s0p[k * 64 + lane] + s1p[k * 64 + lane]) * scale;
        const float* wr = wm + k * TD + dbase;   // wave-uniform -> s_load
#pragma unroll
        for (int j = 0; j < 24; ++j)         // FULL unroll: indexes sA
            sA[j] = fmaf(wr[j], c0, sA[j]);
    }
    float* op = out + (pair * TD + dbase) * HW + y * W + x;
#pragma unroll
    for (int j = 0; j < 24; ++j)             // FULL unroll: indexes sA
        op[j * HW] = sA[j];
}

__global__ __launch_bounds__(512, 8)
void cost_tokenizer(const float* __restrict__ l1, const float* __restrict__ l2,
                    const float* __restrict__ l3,
                    const float* __restrict__ w1, const float* __restrict__ b1,
                    const float* __restrict__ w2, const float* __restrict__ b2,
                    const float* __restrict__ w3, const float* __restrict__ b3,
                    float* __restrict__ out)
{
    __shared__ __align__(16) float smem[8320];  // 8 x 10 x 26 float4 = 33.3 KB
    int bid = blockIdx.x;
    // heavy levels first: L3 (6 chunks/wave), L2 (4), L1 (2)
    if (bid < 64) {
        level_tile<192, 32, 32, 2, 8>(l3, w3, b3, out + 15728640,
                                      bid, 0.072168783648703216f, smem);
    } else if (bid < 320) {
        level_tile<128, 64, 64, 4, 16>(l2, w2, b2, out + 12582912,
                                       bid - 64, 0.088388347648318447f, smem);
    } else {
        level_tile<64, 128, 128, 8, 32>(l1, w1, b1, out,
                                        bid - 320, 0.125f, smem);
    }
}

extern "C" void kernel_launch(void* const* d_in, const int* in_sizes, int n_in,
                              void* d_out, int out_size, void* d_ws, size_t ws_size,
                              hipStream_t stream)
{
    const float* l1 = (const float*)d_in[0];
    const float* l2 = (const float*)d_in[1];
    const float* l3 = (const float*)d_in[2];
    const float* w1 = (const float*)d_in[3];
    const float* b1 = (const float*)d_in[4];
    const float* w2 = (const float*)d_in[5];
    const float* b2 = (const float*)d_in[6];
    const float* w3 = (const float*)d_in[7];
    const float* b3 = (const float*)d_in[8];
    float* out = (float*)d_out;

    hipLaunchKernelGGL(cost_tokenizer, dim3(1344), dim3(512), 0, stream,
                       l1, l2, l3, w1, b1, w2, b2, w3, b3, out);
}

// Round 7
// 311.156 us; speedup vs baseline: 1.1620x; 1.1620x over previous
//
#include <hip/hip_runtime.h>

// CostTokenizer R13: R12's 8-wave C-split, with a sane register budget.
//   Post-mortem R12: __launch_bounds__(512,8) => 4 blocks/CU of 8 waves =
//   2048 resident threads => allocator budgeted VGPR=32; acc[49]+sA[24]
//   spilled catastrophically (WRITE 64.5->230 MB, VALU 10%, 280 us). BUT
//   occupancy hit 66% - the residency mechanism itself worked (2x R8).
//   RULE (final form): never pass launch_bounds args implying <64 VGPR
//   when per-lane live state ~60 floats. (R9: (256,5); R12: (512,8).)
//   Fix: __launch_bounds__(512,4) -> 128-VGPR budget; compiler picks 64
//   voluntarily with this live state (R8/R10/R11 evidence). At VGPR=64 the
//   HW allows 32 waves/CU; LDS 33.3KB allows 4 blocks x 8 waves = 32 waves
//   -> 2x R8's concurrency, no spill.
//   Pipe check at 2x speed (36us): LDS ~56%, VALU ~52%, HBM ~50% - feasible.
//   Spill gate: WRITE_SIZE must be exactly 64,512 KB.
//  - R6 rule kept: every loop indexing a register array is fully unrolled;
//    `unroll 1` only on loops touching LDS/global alone (scratch-spill trap).
//  - bank conflicts ~5.6M are ~free 2-way aliasing (m136); phase-1 b128
//    reads conflict-free within 8-lane groups.
//  - LDS union (reduce slices alias waves 0-6 halos, all dead at the first
//    barrier) + XCD column swizzle.
//
//  corr[k] = sum_c f1[c,h,w] * f2[c, (h-dy)%H, (w-dx)%W], k = (dy+3)*7 + (dx+3)
//  tok[t,b,d,h,w] = b[d] + (1/sqrt(C)) * sum_k corr[k] * w[k,d]

#define TD 192
#define HSTRIDE 26   // halo row stride in float4

template<int C, int H, int W, int TX, int TY>
__device__ __forceinline__ void level_tile(
    const float* __restrict__ lvl, const float* __restrict__ wm,
    const float* __restrict__ bias, float* __restrict__ out,
    int r, float scale, float* __restrict__ smem)
{
    const int HW = H * W;
    // XCD column-affinity: tiles of one column (pair,tX) are == mod 8 in bid
    const int xcd = r & 7, q = r >> 3;
    const int tY  = q % TY;
    const int col = (q / TY) * 8 + xcd;      // [0, 4*TX)
    const int pair = col / TX, tX = col % TX;

    const int t  = pair >> 1, bb = pair & 1;
    const float* f1 = lvl + (t * 2 + bb) * C * HW;
    const float* f2 = lvl + ((t + 1) * 2 + bb) * C * HW;

    const int tid  = threadIdx.x;
    const int lane = tid & 63;
    const int g    = tid >> 6;               // wave: channel group, 0..7
    const int tx   = lane & 15, ty = lane >> 4;   // lane owns row y0+ty
    const int x0   = tX * 16, y0 = tY * 4;
    const int x    = x0 + tx;
    const int y    = y0 + ty;

    float4* h = (float4*)smem + g * (10 * HSTRIDE);  // wave halo: 10 rows

    // staging offsets for halo cells p in [0,220): row=p/22, col=p%22
    int goff[4], loff[4];
#pragma unroll
    for (int i = 0; i < 4; ++i) {
        int p = lane + i * 64;
        int rr = p / 22, cc = p - rr * 22;
        int gy = y0 - 3 + rr; if (gy < 0) gy += H; if (gy >= H) gy -= H;
        int gx = x0 - 3 + cc; if (gx < 0) gx += W; if (gx >= W) gx -= W;
        goff[i] = gy * W + gx;
        loff[i] = rr * HSTRIDE + cc;
    }

    float acc[49];
#pragma unroll
    for (int k = 0; k < 49; ++k) acc[k] = 0.f;

    // ---- phase 1: correlation, wave-synchronous (wave-private halo) ----
    const int NCH = C / 32;                  // 4-channel chunks per wave (8-way split)
    const float* f2c = f2 + g * (C / 8) * HW;
    const float* f1c = f1 + g * (C / 8) * HW + y * W + x;
#pragma unroll 1
    for (int cg = 0; cg < NCH; ++cg) {       // body touches LDS/global only via
#pragma unroll                               // fully-unrolled inner loops
        for (int i = 0; i < 4; ++i) {
            if (i < 3 || lane < 28) {        // 220 cells
                const float* s = f2c + goff[i];
                float4 v; v.x = s[0]; v.y = s[HW]; v.z = s[2 * HW]; v.w = s[3 * HW];
                h[loff[i]] = v;
            }
        }
        float a0 = f1c[0], a1 = f1c[HW], a2 = f1c[2 * HW], a3 = f1c[3 * HW];
        f2c += 4 * HW; f1c += 4 * HW;
        // same-wave LDS RAW: compiler lgkmcnt waits cover it
#pragma unroll
        for (int b = 0; b < 7; ++b) {        // FULL unroll: indexes acc
            const float4* hp = h + ty * HSTRIDE + (tx + 6 - b);
#pragma unroll
            for (int a = 0; a < 7; ++a) {
                float4 lo = hp[(6 - a) * HSTRIDE];
                float s0 = acc[a * 7 + b];
                s0 = fmaf(a0, lo.x, s0); s0 = fmaf(a1, lo.y, s0);
                s0 = fmaf(a2, lo.z, s0); s0 = fmaf(a3, lo.w, s0);
                acc[a * 7 + b] = s0;
            }
        }
    }

    // ---- phase 2: cross-wave reduce; slices alias dead halo space ----
    __syncthreads();                         // all waves done with halos
    float* s0p = smem;                       // [49][64]
    float* s1p = smem + 49 * 64;
    if (g < 2) {                             // waves 0,1 seed the two slices
        float* dst = g ? s1p : s0p;
#pragma unroll
        for (int k = 0; k < 49; ++k)         // FULL unroll: indexes acc
            dst[k * 64 + lane] = acc[k];
    }
    __syncthreads();                         // seeds visible before adds
    if (g >= 2) {                            // waves 2-7: native ds_add_f32
        float* dst = (g & 1) ? s1p : s0p;
#pragma unroll
        for (int k = 0; k < 49; ++k)         // FULL unroll: indexes acc
            atomicAdd(&dst[k * 64 + lane], acc[k]);
    }
    __syncthreads();

    // ---- phase 3: 49 -> 192, wave g owns d in [24g, 24g+24), 1 px/lane ----
    const int dbase = __builtin_amdgcn_readfirstlane(g * 24);
    float sA[24];
#pragma unroll
    for (int j = 0; j < 24; ++j) sA[j] = bias[dbase + j];
#pragma unroll 2
    for (int k = 0; k < 49; ++k) {           // unroll 2: two w-rows in flight
        float c0 = (s0p[k * 64 + lane] + s1p[k * 64 + lane]) * scale;
        const float* wr = wm + k * TD + dbase;   // wave-uniform -> s_load
#pragma unroll
        for (int j = 0; j < 24; ++j)         // FULL unroll: indexes sA
            sA[j] = fmaf(wr[j], c0, sA[j]);
    }
    float* op = out + (pair * TD + dbase) * HW + y * W + x;
#pragma unroll
    for (int j = 0; j < 24; ++j)             // FULL unroll: indexes sA
        op[j * HW] = sA[j];
}

__global__ __launch_bounds__(512, 4)
void cost_tokenizer(const float* __restrict__ l1, const float* __restrict__ l2,
                    const float* __restrict__ l3,
                    const float* __restrict__ w1, const float* __restrict__ b1,
                    const float* __restrict__ w2, const float* __restrict__ b2,
                    const float* __restrict__ w3, const float* __restrict__ b3,
                    float* __restrict__ out)
{
    __shared__ __align__(16) float smem[8320];  // 8 x 10 x 26 float4 = 33.3 KB
    int bid = blockIdx.x;
    // heavy levels first: L3 (6 chunks/wave), L2 (4), L1 (2)
    if (bid < 64) {
        level_tile<192, 32, 32, 2, 8>(l3, w3, b3, out + 15728640,
                                      bid, 0.072168783648703216f, smem);
    } else if (bid < 320) {
        level_tile<128, 64, 64, 4, 16>(l2, w2, b2, out + 12582912,
                                       bid - 64, 0.088388347648318447f, smem);
    } else {
        level_tile<64, 128, 128, 8, 32>(l1, w1, b1, out,
                                        bid - 320, 0.125f, smem);
    }
}

extern "C" void kernel_launch(void* const* d_in, const int* in_sizes, int n_in,
                              void* d_out, int out_size, void* d_ws, size_t ws_size,
                              hipStream_t stream)
{
    const float* l1 = (const float*)d_in[0];
    const float* l2 = (const float*)d_in[1];
    const float* l3 = (const float*)d_in[2];
    const float* w1 = (const float*)d_in[3];
    const float* b1 = (const float*)d_in[4];
    const float* w2 = (const float*)d_in[5];
    const float* b2 = (const float*)d_in[6];
    const float* w3 = (const float*)d_in[7];
    const float* b3 = (const float*)d_in[8];
    float* out = (float*)d_out;

    hipLaunchKernelGGL(cost_tokenizer, dim3(1344), dim3(512), 0, stream,
                       l1, l2, l3, w1, b1, w2, b2, w3, b3, out);
}

// Round 8
// 178.655 us; speedup vs baseline: 2.0237x; 1.7417x over previous
//
#include <hip/hip_runtime.h>

// CostTokenizer R14: R8 + win[7] ILP, with the compiler's occupancy
//   heuristic explicitly overridden.
//   Post-mortem R12/R13: 8-wave C-split dead (spill at (512,8); clean regs
//   at (512,4) still 232 us / VALU 12% — structure adds serialization
//   faster than waves). Post-mortem R11: win[7] was killed not by the
//   launch-bounds BUDGET (128 allowed) but by the allocator VOLUNTARILY
//   pinning 64 VGPR to target 8 waves/SIMD, re-sinking the batch.
//   Fix: __attribute__((amdgpu_waves_per_eu(2,4))) — max=4 forbids the
//   8-wave/64-reg target. Expect ~96-128 VGPR: HW step 65-128 regs ->
//   4 waves/SIMD = 16 waves/CU = 4 blocks — SAME residency as R8, but
//   each wave holds 7 ds_read_b128 in flight (exposed LDS latency /7).
//   Phase-3 unroll 2: two wave-uniform weight-row s_loads in flight.
//   Gates: VGPR must read 96-128 (64 => heuristic ignored attr => revert
//   to R8 verbatim); WRITE_SIZE must stay exactly 64,512 KB (spill).
//  - RULE (R9/R12): never request bounds implying <64 VGPR with ~60 floats
//    of per-lane live state.
//  - R6 rule: every loop indexing a register array is fully unrolled;
//    `unroll 1` only on loops touching LDS/global alone.
//  - phase-1 b128 reads conflict-free within consecutive-8-lane groups
//    ((2ty+tx)&7 spans 0..7); 5.6M conflict counts are staging 2-way (~free).
//  - LDS union (reduce slices alias dead halos, 25.1 KB) + XCD column swizzle.
//
//  corr[k] = sum_c f1[c,h,w] * f2[c, (h-dy)%H, (w-dx)%W], k = (dy+3)*7 + (dx+3)
//  tok[t,b,d,h,w] = b[d] + (1/sqrt(C)) * sum_k corr[k] * w[k,d]

#define TD 192
#define HSTRIDE 26   // halo row stride in float4

template<int C, int H, int W, int TX, int TY>
__device__ __forceinline__ void level_tile(
    const float* __restrict__ lvl, const float* __restrict__ wm,
    const float* __restrict__ bias, float* __restrict__ out,
    int r, float scale, float* __restrict__ smem)
{
    const int HW = H * W;
    // XCD column-affinity: tiles of one column (pair,tX) are == mod 8 in bid
    const int xcd = r & 7, q = r >> 3;
    const int tY  = q % TY;
    const int col = (q / TY) * 8 + xcd;      // [0, 4*TX)
    const int pair = col / TX, tX = col % TX;

    const int t  = pair >> 1, bb = pair & 1;
    const float* f1 = lvl + (t * 2 + bb) * C * HW;
    const float* f2 = lvl + ((t + 1) * 2 + bb) * C * HW;

    const int tid  = threadIdx.x;
    const int lane = tid & 63;
    const int g    = tid >> 6;               // wave: channel group / d group
    const int tx   = lane & 15, ty = lane >> 4;   // lane owns row y0+ty
    const int x0   = tX * 16, y0 = tY * 4;
    const int x    = x0 + tx;
    const int y    = y0 + ty;

    float4* h = (float4*)smem + g * (10 * HSTRIDE);  // wave halo: 10 rows

    // staging offsets for halo cells p in [0,220): row=p/22, col=p%22
    int goff[4], loff[4];
#pragma unroll
    for (int i = 0; i < 4; ++i) {
        int p = lane + i * 64;
        int rr = p / 22, cc = p - rr * 22;
        int gy = y0 - 3 + rr; if (gy < 0) gy += H; if (gy >= H) gy -= H;
        int gx = x0 - 3 + cc; if (gx < 0) gx += W; if (gx >= W) gx -= W;
        goff[i] = gy * W + gx;
        loff[i] = rr * HSTRIDE + cc;
    }

    float acc[49];
#pragma unroll
    for (int k = 0; k < 49; ++k) acc[k] = 0.f;

    // ---- phase 1: correlation, wave-synchronous (wave-private halo) ----
    const int NCH = C / 16;                  // 4-channel chunks per wave
    const float* f2c = f2 + g * (C / 4) * HW;
    const float* f1c = f1 + g * (C / 4) * HW + y * W + x;
#pragma unroll 1
    for (int cg = 0; cg < NCH; ++cg) {       // body touches LDS/global only via
#pragma unroll                               // fully-unrolled inner loops
        for (int i = 0; i < 4; ++i) {
            if (i < 3 || lane < 28) {        // 220 cells
                const float* s = f2c + goff[i];
                float4 v; v.x = s[0]; v.y = s[HW]; v.z = s[2 * HW]; v.w = s[3 * HW];
                h[loff[i]] = v;
            }
        }
        float a0 = f1c[0], a1 = f1c[HW], a2 = f1c[2 * HW], a3 = f1c[3 * HW];
        f2c += 4 * HW; f1c += 4 * HW;
        // same-wave LDS RAW: compiler lgkmcnt waits cover it
#pragma unroll
        for (int b = 0; b < 7; ++b) {        // FULL unroll: indexes acc/win
            const float4* hp = h + ty * HSTRIDE + (tx + 6 - b);
            float4 win[7];                   // 7 ds_read_b128 in flight
#pragma unroll
            for (int a = 0; a < 7; ++a)
                win[a] = hp[(6 - a) * HSTRIDE];
#pragma unroll
            for (int a = 0; a < 7; ++a) {
                float s0 = acc[a * 7 + b];
                s0 = fmaf(a0, win[a].x, s0); s0 = fmaf(a1, win[a].y, s0);
                s0 = fmaf(a2, win[a].z, s0); s0 = fmaf(a3, win[a].w, s0);
                acc[a * 7 + b] = s0;
            }
        }
    }

    // ---- phase 2: cross-wave reduce; slices alias dead halo space ----
    __syncthreads();                         // all waves done with halos
    float* s0p = smem;                       // [49][64]
    float* s1p = smem + 49 * 64;
    if (g >= 2) {
        float* dst = (g == 2) ? s0p : s1p;
#pragma unroll
        for (int k = 0; k < 49; ++k)         // FULL unroll: indexes acc
            dst[k * 64 + lane] = acc[k];
    }
    __syncthreads();
    if (g < 2) {
        float* dst = (g == 0) ? s0p : s1p;
#pragma unroll
        for (int k = 0; k < 49; ++k)         // FULL unroll: indexes acc
            dst[k * 64 + lane] += acc[k];
    }
    __syncthreads();

    // ---- phase 3: 49 -> 192, wave g owns d in [48g, 48g+48), 1 px/lane ----
    const int dbase = __builtin_amdgcn_readfirstlane(g * 48);
    float sA[48];
#pragma unroll
    for (int j = 0; j < 48; ++j) sA[j] = bias[dbase + j];
#pragma unroll 2
    for (int k = 0; k < 49; ++k) {           // unroll 2: two w-rows in flight
        float c0 = (s0p[k * 64 + lane] + s1p[k * 64 + lane]) * scale;
        const float* wr = wm + k * TD + dbase;   // wave-uniform -> s_load
#pragma unroll
        for (int j = 0; j < 48; ++j)         // FULL unroll: indexes sA
            sA[j] = fmaf(wr[j], c0, sA[j]);
    }
    float* op = out + (pair * TD + dbase) * HW + y * W + x;
#pragma unroll
    for (int j = 0; j < 48; ++j)             // FULL unroll: indexes sA
        op[j * HW] = sA[j];
}

__global__ __launch_bounds__(256) __attribute__((amdgpu_waves_per_eu(2, 4)))
void cost_tokenizer(const float* __restrict__ l1, const float* __restrict__ l2,
                    const float* __restrict__ l3,
                    const float* __restrict__ w1, const float* __restrict__ b1,
                    const float* __restrict__ w2, const float* __restrict__ b2,
                    const float* __restrict__ w3, const float* __restrict__ b3,
                    float* __restrict__ out)
{
    __shared__ __align__(16) float smem[6272];  // max(2*49*64, 4*10*26*4) f = 25.1 KB
    int bid = blockIdx.x;
    // heavy levels first: L3 (12 chunks/wave), L2 (8), L1 (4)
    if (bid < 64) {
        level_tile<192, 32, 32, 2, 8>(l3, w3, b3, out + 15728640,
                                      bid, 0.072168783648703216f, smem);
    } else if (bid < 320) {
        level_tile<128, 64, 64, 4, 16>(l2, w2, b2, out + 12582912,
                                       bid - 64, 0.088388347648318447f, smem);
    } else {
        level_tile<64, 128, 128, 8, 32>(l1, w1, b1, out,
                                        bid - 320, 0.125f, smem);
    }
}

extern "C" void kernel_launch(void* const* d_in, const int* in_sizes, int n_in,
                              void* d_out, int out_size, void* d_ws, size_t ws_size,
                              hipStream_t stream)
{
    const float* l1 = (const float*)d_in[0];
    const float* l2 = (const float*)d_in[1];
    const float* l3 = (const float*)d_in[2];
    const float* w1 = (const float*)d_in[3];
    const float* b1 = (const float*)d_in[4];
    const float* w2 = (const float*)d_in[5];
    const float* b2 = (const float*)d_in[6];
    const float* w3 = (const float*)d_in[7];
    const float* b3 = (const float*)d_in[8];
    float* out = (float*)d_out;

    hipLaunchKernelGGL(cost_tokenizer, dim3(1344), dim3(256), 0, stream,
                       l1, l2, l3, w1, b1, w2, b2, w3, b3, out);
}

// Round 9
// 172.049 us; speedup vs baseline: 2.1014x; 1.0384x over previous
//
#include <hip/hip_runtime.h>

// CostTokenizer R15: R8 rolling-FMA body + R10 chunk-prefetch +
//   amdgpu_waves_per_eu(2,4). The two halves failed alone for DISJOINT
//   reasons, both now understood:
//   - R10 (prefetch @ bounds(256,4)): allocator VOLUNTARILY pinned 60 VGPR
//     (8-wave heuristic) and serialized the staged loads -> 91 us.
//   - R11/R14 (win[7] batch @ 64 and @ 68 regs, no spill): both 97-98 us
//     -> exposed ds_read latency is NOT the stall; batching only delays FMA.
//   - R14 proved waves_per_eu(2,4) moves the allocator off the 64 pin.
//   Stall model for R8 (72 us): per chunk, ~20 global loads issue with
//   NOTHING between issue and vmcnt use -> ~700 cy exposed per chunk per
//   wave vs ~800 cy compute; 4 waves/SIMD cover only half -> VALU 37%.
//   Fix: prefetch next chunk's f2-gather (4xfloat4) + f1 quad into regs
//   before the FMA block; with the 128-reg budget the scheduler can keep
//   them in flight. Residency unchanged (4 waves/SIMD, block-limited).
//   Gates: VGPR must read 85-110 (60-68 => loads re-sunk => inline-asm
//   next); WRITE_SIZE exactly 64,512 KB (spill).
//  - RULE (R9/R12): never request bounds implying <64 VGPR with ~60 floats
//    of per-lane live state. waves_per_eu max=4 raises, never lowers, budget.
//  - R6 rule: loops indexing register arrays are fully unrolled; `unroll 1`
//    only on loops touching LDS/global alone.
//  - 8-wave C-split dead (R12 spill / R13 serialization); win-batch dead
//    (R11/R14); split-k dead (R7). Best-known: R8 = 72 us.
//  - LDS union (reduce slices alias dead halos, 25.1 KB) + XCD column swizzle.
//
//  corr[k] = sum_c f1[c,h,w] * f2[c, (h-dy)%H, (w-dx)%W], k = (dy+3)*7 + (dx+3)
//  tok[t,b,d,h,w] = b[d] + (1/sqrt(C)) * sum_k corr[k] * w[k,d]

#define TD 192
#define HSTRIDE 26   // halo row stride in float4

template<int C, int H, int W, int TX, int TY>
__device__ __forceinline__ void level_tile(
    const float* __restrict__ lvl, const float* __restrict__ wm,
    const float* __restrict__ bias, float* __restrict__ out,
    int r, float scale, float* __restrict__ smem)
{
    const int HW = H * W;
    // XCD column-affinity: tiles of one column (pair,tX) are == mod 8 in bid
    const int xcd = r & 7, q = r >> 3;
    const int tY  = q % TY;
    const int col = (q / TY) * 8 + xcd;      // [0, 4*TX)
    const int pair = col / TX, tX = col % TX;

    const int t  = pair >> 1, bb = pair & 1;
    const float* f1 = lvl + (t * 2 + bb) * C * HW;
    const float* f2 = lvl + ((t + 1) * 2 + bb) * C * HW;

    const int tid  = threadIdx.x;
    const int lane = tid & 63;
    const int g    = tid >> 6;               // wave: channel group / d group
    const int tx   = lane & 15, ty = lane >> 4;   // lane owns row y0+ty
    const int x0   = tX * 16, y0 = tY * 4;
    const int x    = x0 + tx;
    const int y    = y0 + ty;

    float4* h = (float4*)smem + g * (10 * HSTRIDE);  // wave halo: 10 rows

    // staging offsets for halo cells p in [0,220): row=p/22, col=p%22
    int goff[4], loff[4];
#pragma unroll
    for (int i = 0; i < 4; ++i) {
        int p = lane + i * 64;
        int rr = p / 22, cc = p - rr * 22;
        int gy = y0 - 3 + rr; if (gy < 0) gy += H; if (gy >= H) gy -= H;
        int gx = x0 - 3 + cc; if (gx < 0) gx += W; if (gx >= W) gx -= W;
        goff[i] = gy * W + gx;
        loff[i] = rr * HSTRIDE + cc;
    }

    float acc[49];
#pragma unroll
    for (int k = 0; k < 49; ++k) acc[k] = 0.f;

    // ---- phase 1: correlation, wave-synchronous (wave-private halo) ----
    const int NCH = C / 16;                  // 4-channel chunks per wave
    const float* f2c = f2 + g * (C / 4) * HW;
    const float* f1c = f1 + g * (C / 4) * HW + y * W + x;

    float4 pv[4], pa;                        // register-staged next chunk
#pragma unroll
    for (int i = 0; i < 4; ++i) {            // prologue: gather chunk 0
        const float* s = f2c + goff[i];
        pv[i].x = s[0]; pv[i].y = s[HW]; pv[i].z = s[2 * HW]; pv[i].w = s[3 * HW];
    }
    pa.x = f1c[0]; pa.y = f1c[HW]; pa.z = f1c[2 * HW]; pa.w = f1c[3 * HW];

#pragma unroll 1
    for (int cg = 0; cg < NCH; ++cg) {       // body touches LDS/global only via
        // commit staged halo to LDS (wave-private; same-wave order is safe)
#pragma unroll                               // fully-unrolled inner loops
        for (int i = 0; i < 4; ++i)
            if (i < 3 || lane < 28) h[loff[i]] = pv[i];
        float a0 = pa.x, a1 = pa.y, a2 = pa.z, a3 = pa.w;
        f2c += 4 * HW; f1c += 4 * HW;
        if (cg + 1 < NCH) {                  // issue NEXT chunk's gathers now:
#pragma unroll                               // latency hides under FMA below
            for (int i = 0; i < 4; ++i) {
                const float* s = f2c + goff[i];
                pv[i].x = s[0]; pv[i].y = s[HW]; pv[i].z = s[2 * HW]; pv[i].w = s[3 * HW];
            }
            pa.x = f1c[0]; pa.y = f1c[HW]; pa.z = f1c[2 * HW]; pa.w = f1c[3 * HW];
        }
        // same-wave LDS RAW: compiler lgkmcnt waits cover it
#pragma unroll
        for (int b = 0; b < 7; ++b) {        // FULL unroll: indexes acc
            const float4* hp = h + ty * HSTRIDE + (tx + 6 - b);
#pragma unroll
            for (int a = 0; a < 7; ++a) {
                float4 lo = hp[(6 - a) * HSTRIDE];
                float s0 = acc[a * 7 + b];
                s0 = fmaf(a0, lo.x, s0); s0 = fmaf(a1, lo.y, s0);
                s0 = fmaf(a2, lo.z, s0); s0 = fmaf(a3, lo.w, s0);
                acc[a * 7 + b] = s0;
            }
        }
    }

    // ---- phase 2: cross-wave reduce; slices alias dead halo space ----
    __syncthreads();                         // all waves done with halos
    float* s0p = smem;                       // [49][64]
    float* s1p = smem + 49 * 64;
    if (g >= 2) {
        float* dst = (g == 2) ? s0p : s1p;
#pragma unroll
        for (int k = 0; k < 49; ++k)         // FULL unroll: indexes acc
            dst[k * 64 + lane] = acc[k];
    }
    __syncthreads();
    if (g < 2) {
        float* dst = (g == 0) ? s0p : s1p;
#pragma unroll
        for (int k = 0; k < 49; ++k)         // FULL unroll: indexes acc
            dst[k * 64 + lane] += acc[k];
    }
    __syncthreads();

    // ---- phase 3: 49 -> 192, wave g owns d in [48g, 48g+48), 1 px/lane ----
    const int dbase = __builtin_amdgcn_readfirstlane(g * 48);
    float sA[48];
#pragma unroll
    for (int j = 0; j < 48; ++j) sA[j] = bias[dbase + j];
#pragma unroll 2
    for (int k = 0; k < 49; ++k) {           // unroll 2: two w-rows in flight
        float c0 = (s0p[k * 64 + lane] + s1p[k * 64 + lane]) * scale;
        const float* wr = wm + k * TD + dbase;   // wave-uniform -> s_load
#pragma unroll
        for (int j = 0; j < 48; ++j)         // FULL unroll: indexes sA
            sA[j] = fmaf(wr[j], c0, sA[j]);
    }
    float* op = out + (pair * TD + dbase) * HW + y * W + x;
#pragma unroll
    for (int j = 0; j < 48; ++j)             // FULL unroll: indexes sA
        op[j * HW] = sA[j];
}

__global__ __launch_bounds__(256) __attribute__((amdgpu_waves_per_eu(2, 4)))
void cost_tokenizer(const float* __restrict__ l1, const float* __restrict__ l2,
                    const float* __restrict__ l3,
                    const float* __restrict__ w1, const float* __restrict__ b1,
                    const float* __restrict__ w2, const float* __restrict__ b2,
                    const float* __restrict__ w3, const float* __restrict__ b3,
                    float* __restrict__ out)
{
    __shared__ __align__(16) float smem[6272];  // max(2*49*64, 4*10*26*4) f = 25.1 KB
    int bid = blockIdx.x;
    // heavy levels first: L3 (12 chunks/wave), L2 (8), L1 (4)
    if (bid < 64) {
        level_tile<192, 32, 32, 2, 8>(l3, w3, b3, out + 15728640,
                                      bid, 0.072168783648703216f, smem);
    } else if (bid < 320) {
        level_tile<128, 64, 64, 4, 16>(l2, w2, b2, out + 12582912,
                                       bid - 64, 0.088388347648318447f, smem);
    } else {
        level_tile<64, 128, 128, 8, 32>(l1, w1, b1, out,
                                        bid - 320, 0.125f, smem);
    }
}

extern "C" void kernel_launch(void* const* d_in, const int* in_sizes, int n_in,
                              void* d_out, int out_size, void* d_ws, size_t ws_size,
                              hipStream_t stream)
{
    const float* l1 = (const float*)d_in[0];
    const float* l2 = (const float*)d_in[1];
    const float* l3 = (const float*)d_in[2];
    const float* w1 = (const float*)d_in[3];
    const float* b1 = (const float*)d_in[4];
    const float* w2 = (const float*)d_in[5];
    const float* b2 = (const float*)d_in[6];
    const float* w3 = (const float*)d_in[7];
    const float* b3 = (const float*)d_in[8];
    float* out = (float*)d_out;

    hipLaunchKernelGGL(cost_tokenizer, dim3(1344), dim3(256), 0, stream,
                       l1, l2, l3, w1, b1, w2, b2, w3, b3, out);
}

// Round 10
// 170.351 us; speedup vs baseline: 2.1224x; 1.0100x over previous
//
#include <hip/hip_runtime.h>

// CostTokenizer R16: prefetch, PHYSICALLY PINNED with sched_barrier(0).
//   Post-mortem R9-R15: five scheduling attempts, one root cause — the
//   pre-RA scheduler sinks register-staged global loads to their uses
//   regardless of budget (R15: waves_per_eu(2,4) granted 128 regs, VGPR
//   still 60 -> loads serialized, 86 us). Register budget is permission;
//   only a motion fence is instruction.
//   Fix (guide rule #18 / T14): two __builtin_amdgcn_sched_barrier(0)
//   pins per phase-1 iteration:
//     pin A (body top): new prefetch cannot hoist above the ds_write's
//       vmcnt drain of the OLD prefetch (would convoy the pipeline);
//     pin B (after prefetch issue): loads cannot sink into/below the
//       FMA block -> ~700 cy global latency hides under ~800 cy issue.
//   Allocator outcome is now binary and counter-visible:
//     keep pv/pa live -> VGPR 85-110 (the win)   | spill -> WRITE_SIZE alarm.
//   Gates: VGPR 85-110; WRITE_SIZE exactly 64,512 KB; else read per header.
//  - RULE (R9/R12): never request bounds implying <64 VGPR with ~60 floats
//    live. waves_per_eu(2,4) kept: budget 128, HW step 65-128 = 4 waves/SIMD.
//  - R6 rule: loops indexing register arrays fully unrolled; `unroll 1`
//    only on loops touching LDS/global alone.
//  - Dead ends: 8-wave C-split (R12/R13), win[7] batch (R11/R14), split-k
//    (R7), unpinned prefetch (R10/R15). Best-known: R8 = 72 us/dispatch.
//  - LDS union (reduce slices alias dead halos, 25.1 KB) + XCD column swizzle.
//
//  corr[k] = sum_c f1[c,h,w] * f2[c, (h-dy)%H, (w-dx)%W], k = (dy+3)*7 + (dx+3)
//  tok[t,b,d,h,w] = b[d] + (1/sqrt(C)) * sum_k corr[k] * w[k,d]

#define TD 192
#define HSTRIDE 26   // halo row stride in float4

template<int C, int H, int W, int TX, int TY>
__device__ __forceinline__ void level_tile(
    const float* __restrict__ lvl, const float* __restrict__ wm,
    const float* __restrict__ bias, float* __restrict__ out,
    int r, float scale, float* __restrict__ smem)
{
    const int HW = H * W;
    // XCD column-affinity: tiles of one column (pair,tX) are == mod 8 in bid
    const int xcd = r & 7, q = r >> 3;
    const int tY  = q % TY;
    const int col = (q / TY) * 8 + xcd;      // [0, 4*TX)
    const int pair = col / TX, tX = col % TX;

    const int t  = pair >> 1, bb = pair & 1;
    const float* f1 = lvl + (t * 2 + bb) * C * HW;
    const float* f2 = lvl + ((t + 1) * 2 + bb) * C * HW;

    const int tid  = threadIdx.x;
    const int lane = tid & 63;
    const int g    = tid >> 6;               // wave: channel group / d group
    const int tx   = lane & 15, ty = lane >> 4;   // lane owns row y0+ty
    const int x0   = tX * 16, y0 = tY * 4;
    const int x    = x0 + tx;
    const int y    = y0 + ty;

    float4* h = (float4*)smem + g * (10 * HSTRIDE);  // wave halo: 10 rows

    // staging offsets for halo cells p in [0,220): row=p/22, col=p%22
    int goff[4], loff[4];
#pragma unroll
    for (int i = 0; i < 4; ++i) {
        int p = lane + i * 64;
        int rr = p / 22, cc = p - rr * 22;
        int gy = y0 - 3 + rr; if (gy < 0) gy += H; if (gy >= H) gy -= H;
        int gx = x0 - 3 + cc; if (gx < 0) gx += W; if (gx >= W) gx -= W;
        goff[i] = gy * W + gx;
        loff[i] = rr * HSTRIDE + cc;
    }

    float acc[49];
#pragma unroll
    for (int k = 0; k < 49; ++k) acc[k] = 0.f;

    // ---- phase 1: correlation, wave-synchronous (wave-private halo) ----
    const int NCH = C / 16;                  // 4-channel chunks per wave
    const float* f2c = f2 + g * (C / 4) * HW;
    const float* f1c = f1 + g * (C / 4) * HW + y * W + x;

    float4 pv[4], pa;                        // register-staged next chunk
#pragma unroll
    for (int i = 0; i < 4; ++i) {            // prologue: gather chunk 0
        const float* s = f2c + goff[i];
        pv[i].x = s[0]; pv[i].y = s[HW]; pv[i].z = s[2 * HW]; pv[i].w = s[3 * HW];
    }
    pa.x = f1c[0]; pa.y = f1c[HW]; pa.z = f1c[2 * HW]; pa.w = f1c[3 * HW];

#pragma unroll 1
    for (int cg = 0; cg < NCH; ++cg) {
        // pin A: nothing from below (incl. next prefetch) may hoist above
        // the ds_write region and its vmcnt drain of the OLD prefetch.
        __builtin_amdgcn_sched_barrier(0);
        // commit staged halo to LDS (wave-private; same-wave order is safe)
#pragma unroll                               // fully-unrolled inner loops
        for (int i = 0; i < 4; ++i)
            if (i < 3 || lane < 28) h[loff[i]] = pv[i];
        float a0 = pa.x, a1 = pa.y, a2 = pa.z, a3 = pa.w;
        f2c += 4 * HW; f1c += 4 * HW;
        if (cg + 1 < NCH) {                  // issue NEXT chunk's gathers now
#pragma unroll
            for (int i = 0; i < 4; ++i) {
                const float* s = f2c + goff[i];
                pv[i].x = s[0]; pv[i].y = s[HW]; pv[i].z = s[2 * HW]; pv[i].w = s[3 * HW];
            }
            pa.x = f1c[0]; pa.y = f1c[HW]; pa.z = f1c[2 * HW]; pa.w = f1c[3 * HW];
        }
        // pin B: the loads above may NOT sink into/below the FMA block.
        __builtin_amdgcn_sched_barrier(0);
        // same-wave LDS RAW: compiler lgkmcnt waits cover it
#pragma unroll
        for (int b = 0; b < 7; ++b) {        // FULL unroll: indexes acc
            const float4* hp = h + ty * HSTRIDE + (tx + 6 - b);
#pragma unroll
            for (int a = 0; a < 7; ++a) {
                float4 lo = hp[(6 - a) * HSTRIDE];
                float s0 = acc[a * 7 + b];
                s0 = fmaf(a0, lo.x, s0); s0 = fmaf(a1, lo.y, s0);
                s0 = fmaf(a2, lo.z, s0); s0 = fmaf(a3, lo.w, s0);
                acc[a * 7 + b] = s0;
            }
        }
    }

    // ---- phase 2: cross-wave reduce; slices alias dead halo space ----
    __syncthreads();                         // all waves done with halos
    float* s0p = smem;                       // [49][64]
    float* s1p = smem + 49 * 64;
    if (g >= 2) {
        float* dst = (g == 2) ? s0p : s1p;
#pragma unroll
        for (int k = 0; k < 49; ++k)         // FULL unroll: indexes acc
            dst[k * 64 + lane] = acc[k];
    }
    __syncthreads();
    if (g < 2) {
        float* dst = (g == 0) ? s0p : s1p;
#pragma unroll
        for (int k = 0; k < 49; ++k)         // FULL unroll: indexes acc
            dst[k * 64 + lane] += acc[k];
    }
    __syncthreads();

    // ---- phase 3: 49 -> 192, wave g owns d in [48g, 48g+48), 1 px/lane ----
    const int dbase = __builtin_amdgcn_readfirstlane(g * 48);
    float sA[48];
#pragma unroll
    for (int j = 0; j < 48; ++j) sA[j] = bias[dbase + j];
#pragma unroll 2
    for (int k = 0; k < 49; ++k) {           // unroll 2: two w-rows in flight
        float c0 = (s0p[k * 64 + lane] + s1p[k * 64 + lane]) * scale;
        const float* wr = wm + k * TD + dbase;   // wave-uniform -> s_load
#pragma unroll
        for (int j = 0; j < 48; ++j)         // FULL unroll: indexes sA
            sA[j] = fmaf(wr[j], c0, sA[j]);
    }
    float* op = out + (pair * TD + dbase) * HW + y * W + x;
#pragma unroll
    for (int j = 0; j < 48; ++j)             // FULL unroll: indexes sA
        op[j * HW] = sA[j];
}

__global__ __launch_bounds__(256) __attribute__((amdgpu_waves_per_eu(2, 4)))
void cost_tokenizer(const float* __restrict__ l1, const float* __restrict__ l2,
                    const float* __restrict__ l3,
                    const float* __restrict__ w1, const float* __restrict__ b1,
                    const float* __restrict__ w2, const float* __restrict__ b2,
                    const float* __restrict__ w3, const float* __restrict__ b3,
                    float* __restrict__ out)
{
    __shared__ __align__(16) float smem[6272];  // max(2*49*64, 4*10*26*4) f = 25.1 KB
    int bid = blockIdx.x;
    // heavy levels first: L3 (12 chunks/wave), L2 (8), L1 (4)
    if (bid < 64) {
        level_tile<192, 32, 32, 2, 8>(l3, w3, b3, out + 15728640,
                                      bid, 0.072168783648703216f, smem);
    } else if (bid < 320) {
        level_tile<128, 64, 64, 4, 16>(l2, w2, b2, out + 12582912,
                                       bid - 64, 0.088388347648318447f, smem);
    } else {
        level_tile<64, 128, 128, 8, 32>(l1, w1, b1, out,
                                        bid - 320, 0.125f, smem);
    }
}

extern "C" void kernel_launch(void* const* d_in, const int* in_sizes, int n_in,
                              void* d_out, int out_size, void* d_ws, size_t ws_size,
                              hipStream_t stream)
{
    const float* l1 = (const float*)d_in[0];
    const float* l2 = (const float*)d_in[1];
    const float* l3 = (const float*)d_in[2];
    const float* w1 = (const float*)d_in[3];
    const float* b1 = (const float*)d_in[4];
    const float* w2 = (const float*)d_in[5];
    const float* b2 = (const float*)d_in[6];
    const float* w3 = (const float*)d_in[7];
    const float* b3 = (const float*)d_in[8];
    float* out = (float*)d_out;

    hipLaunchKernelGGL(cost_tokenizer, dim3(1344), dim3(256), 0, stream,
                       l1, l2, l3, w1, b1, w2, b2, w3, b3, out);
}